// Round 9
// baseline (642.154 us; speedup 1.0000x reference)
//
#include <hip/hip_runtime.h>

#define N_NODES 100000
#define DIM 64
#define N_EDGES 1250000
#define EPS 1e-12f

#define PART 128                          // nodes per partition
#define NP ((N_NODES + PART - 1) / PART)  // 782 partitions
#define SLOT 2048                         // edge slots/partition (mean 1600, +11 sigma)
#define CH 4096                           // edges per bucket block
#define NCH ((N_EDGES + CH - 1) / CH)     // 306 bucket blocks
#define BT 512                            // bucket block threads
#define EPT (CH / BT)                     // 8 edges per thread

typedef unsigned short ushort8 __attribute__((ext_vector_type(8)));

__device__ inline unsigned short f2bf(float f) {   // fp32 -> bf16 RNE
    unsigned int u = __float_as_uint(f);
    return (unsigned short)((u + 0x7FFFu + ((u >> 16) & 1u)) >> 16);
}
__device__ inline float bf2f(unsigned short h) {
    return __uint_as_float(((unsigned int)h) << 16);
}

// ---- Pass 0: x (fp32) -> xh (bf16); halves gather traffic ----
__global__ void convert_kernel(const float4* __restrict__ x4,
                               ushort8* __restrict__ xh8) {
    int i = blockIdx.x * blockDim.x + threadIdx.x;
    if (i < N_NODES * DIM / 8) {
        float4 a = x4[2 * i];
        float4 b = x4[2 * i + 1];
        ushort8 o;
        o[0] = f2bf(a.x); o[1] = f2bf(a.y); o[2] = f2bf(a.z); o[3] = f2bf(a.w);
        o[4] = f2bf(b.x); o[5] = f2bf(b.y); o[6] = f2bf(b.z); o[7] = f2bf(b.w);
        xh8[i] = o;
    }
}

// ---- Pass 1: bucket edges by dst partition. Per-block LDS histogram over
// 782 bins; ONE returning global atomic per (block, partition) — 239K total
// vs 1.25M per-edge (the measured ~25 G ops/s wall). Packed edge =
// (src << 7) | local_dst scattered into per-partition slabs.
__global__ void bucket_kernel(const int* __restrict__ src,
                              const int* __restrict__ dst,
                              int* __restrict__ pcursor,
                              int* __restrict__ ebuf) {
    __shared__ int lhist[NP];
    __shared__ int gb[NP];
    int t = threadIdx.x;
    int e0 = blockIdx.x * CH;

    for (int p = t; p < NP; p += BT) lhist[p] = 0;
    __syncthreads();

    int d[EPT];
    #pragma unroll
    for (int i = 0; i < EPT; ++i) {
        int e = e0 + i * BT + t;
        if (e < N_EDGES) {
            d[i] = dst[e];
            atomicAdd(&lhist[d[i] >> 7], 1);       // LDS, non-returning
        } else {
            d[i] = -1;
        }
    }
    __syncthreads();

    for (int p = t; p < NP; p += BT) {
        int c = lhist[p];
        gb[p] = c ? atomicAdd(&pcursor[p], c) : 0; // global, block-granular
        lhist[p] = 0;
    }
    __syncthreads();

    #pragma unroll
    for (int i = 0; i < EPT; ++i) {
        if (d[i] >= 0) {
            int e = e0 + i * BT + t;
            int p = d[i] >> 7;
            int loc = atomicAdd(&lhist[p], 1);     // LDS, returning (fast)
            ebuf[p * SLOT + gb[p] + loc] = (src[e] << 7) | (d[i] & 127);
        }
    }
}

// ---- Pass 2: one block per partition. Accumulate gathered bf16 rows into a
// 32 KB LDS fp32 accumulator (ds_add_f32, non-returning, conflict-free);
// fused mean + L2-normalize + relu(2h) epilogue from LDS.
__global__ __launch_bounds__(1024, 8)
void aggregate_kernel(const unsigned short* __restrict__ xh,
                      const int* __restrict__ pcursor,
                      const int* __restrict__ ebuf,
                      float* __restrict__ out) {
    __shared__ float acc[PART * DIM];   // 32 KB -> 2 blocks/CU (32 waves/CU)
    __shared__ int dcnt[PART];
    int p = blockIdx.x;
    int t = threadIdx.x;
    int wave = t >> 6, lane = t & 63;

    for (int i = t; i < PART * DIM; i += 1024) acc[i] = 0.0f;
    if (t < PART) dcnt[t] = 0;
    __syncthreads();

    int cnt = pcursor[p];
    const int* __restrict__ eb = ebuf + p * SLOT;

    // 16 waves stride the partition's edges; unroll x4 for 4 outstanding
    // 128 B gathers per wave (x32 waves/CU = latency covered).
    int e = wave;
    for (; e + 48 < cnt; e += 64) {
        int pk0 = eb[e];
        int pk1 = eb[e + 16];
        int pk2 = eb[e + 32];
        int pk3 = eb[e + 48];
        float v0 = bf2f(xh[(size_t)(pk0 >> 7) * DIM + lane]);
        float v1 = bf2f(xh[(size_t)(pk1 >> 7) * DIM + lane]);
        float v2 = bf2f(xh[(size_t)(pk2 >> 7) * DIM + lane]);
        float v3 = bf2f(xh[(size_t)(pk3 >> 7) * DIM + lane]);
        atomicAdd(&acc[(pk0 & 127) * DIM + lane], v0);
        atomicAdd(&acc[(pk1 & 127) * DIM + lane], v1);
        atomicAdd(&acc[(pk2 & 127) * DIM + lane], v2);
        atomicAdd(&acc[(pk3 & 127) * DIM + lane], v3);
        if (lane == 0) {
            atomicAdd(&dcnt[pk0 & 127], 1);
            atomicAdd(&dcnt[pk1 & 127], 1);
            atomicAdd(&dcnt[pk2 & 127], 1);
            atomicAdd(&dcnt[pk3 & 127], 1);
        }
    }
    for (; e < cnt; e += 16) {
        int pk = eb[e];
        float v = bf2f(xh[(size_t)(pk >> 7) * DIM + lane]);
        atomicAdd(&acc[(pk & 127) * DIM + lane], v);
        if (lane == 0) atomicAdd(&dcnt[pk & 127], 1);
    }
    __syncthreads();

    // Epilogue: 8 threads per node (k = dim octet), shfl-reduce sumsq.
    int nl = t >> 3;             // local node 0..127
    int k  = t & 7;              // dim octet 0..7
    int gnode = p * PART + nl;
    if (gnode < N_NODES) {
        float4 a = *(float4*)&acc[nl * DIM + k * 8];
        float4 b = *(float4*)&acc[nl * DIM + k * 8 + 4];
        float inv = 1.0f / fmaxf((float)dcnt[nl], 1.0f);
        a.x *= inv; a.y *= inv; a.z *= inv; a.w *= inv;
        b.x *= inv; b.y *= inv; b.z *= inv; b.w *= inv;
        float ss = a.x * a.x + a.y * a.y + a.z * a.z + a.w * a.w
                 + b.x * b.x + b.y * b.y + b.z * b.z + b.w * b.w;
        ss += __shfl_xor(ss, 1, 64);   // 8-lane group reduce (lanes 8-aligned)
        ss += __shfl_xor(ss, 2, 64);
        ss += __shfl_xor(ss, 4, 64);
        float scale = 2.0f / fmaxf(sqrtf(ss), EPS);
        float4 o0, o1;
        o0.x = fmaxf(a.x * scale, 0.0f); o0.y = fmaxf(a.y * scale, 0.0f);
        o0.z = fmaxf(a.z * scale, 0.0f); o0.w = fmaxf(a.w * scale, 0.0f);
        o1.x = fmaxf(b.x * scale, 0.0f); o1.y = fmaxf(b.y * scale, 0.0f);
        o1.z = fmaxf(b.z * scale, 0.0f); o1.w = fmaxf(b.w * scale, 0.0f);
        ((float4*)out)[(size_t)gnode * 16 + k * 2]     = o0;
        ((float4*)out)[(size_t)gnode * 16 + k * 2 + 1] = o1;
    }
}

extern "C" void kernel_launch(void* const* d_in, const int* in_sizes, int n_in,
                              void* d_out, int out_size, void* d_ws, size_t ws_size,
                              hipStream_t stream) {
    const float* x  = (const float*)d_in[0];
    const int*   ei = (const int*)d_in[1];
    float* out = (float*)d_out;

    const int* src = ei;
    const int* dst = ei + N_EDGES;

    // ws: xh[12.8 MB bf16] | pcursor[782] | ebuf[782*2048 int = 6.4 MB]
    ushort8* xh  = (ushort8*)d_ws;
    int* pcursor = (int*)((char*)d_ws + (size_t)N_NODES * DIM * 2);
    int* ebuf    = pcursor + NP;

    hipMemsetAsync(pcursor, 0, NP * sizeof(int), stream);

    int cvb = (N_NODES * DIM / 8 + 255) / 256;
    convert_kernel<<<cvb, 256, 0, stream>>>((const float4*)x, xh);

    bucket_kernel<<<NCH, BT, 0, stream>>>(src, dst, pcursor, ebuf);

    aggregate_kernel<<<NP, 1024, 0, stream>>>((const unsigned short*)xh,
                                              pcursor, ebuf, out);
}

// Round 10
// 174.568 us; speedup vs baseline: 3.6785x; 3.6785x over previous
//
#include <hip/hip_runtime.h>

#define N_NODES 100000
#define DIM 64
#define N_EDGES 1250000
#define EPS 1e-12f

#define PART 128                          // nodes per partition
#define NP ((N_NODES + PART - 1) / PART)  // 782 partitions
#define SLOT 2048                         // edge slots/partition (mean 1600, +11 sigma)
#define CSTRIDE 16                        // pcursor padding: 1 cursor per 64B line
#define CH 16384                          // edges per bucket block
#define NCH ((N_EDGES + CH - 1) / CH)     // 77 bucket blocks
#define BT 1024                           // bucket block threads
#define EPT (CH / BT)                     // 16 edges per thread

typedef unsigned short ushort8 __attribute__((ext_vector_type(8)));

__device__ inline unsigned short f2bf(float f) {   // fp32 -> bf16 RNE
    unsigned int u = __float_as_uint(f);
    return (unsigned short)((u + 0x7FFFu + ((u >> 16) & 1u)) >> 16);
}
__device__ inline float bf2f(unsigned short h) {
    return __uint_as_float(((unsigned int)h) << 16);
}

// ---- Pass 0: x (fp32) -> xh (bf16); halves gather traffic ----
__global__ void convert_kernel(const float4* __restrict__ x4,
                               ushort8* __restrict__ xh8) {
    int i = blockIdx.x * blockDim.x + threadIdx.x;
    if (i < N_NODES * DIM / 8) {
        float4 a = x4[2 * i];
        float4 b = x4[2 * i + 1];
        ushort8 o;
        o[0] = f2bf(a.x); o[1] = f2bf(a.y); o[2] = f2bf(a.z); o[3] = f2bf(a.w);
        o[4] = f2bf(b.x); o[5] = f2bf(b.y); o[6] = f2bf(b.z); o[7] = f2bf(b.w);
        xh8[i] = o;
    }
}

// ---- Pass 1: bucket edges by dst partition. 77 big blocks -> only 60K
// block-granular returning global atomics (global wall is ~25 G ops/s on
// per-edge returning atomics; this is 20x under it). Cursors padded to one
// per 64 B line. Packed edge = (src << 7) | local_dst.
__global__ __launch_bounds__(BT)
void bucket_kernel(const int* __restrict__ src,
                   const int* __restrict__ dst,
                   int* __restrict__ pcursor,
                   int* __restrict__ ebuf) {
    __shared__ int lhist[NP];
    __shared__ int gb[NP];
    int t = threadIdx.x;
    int e0 = blockIdx.x * CH;

    for (int p = t; p < NP; p += BT) lhist[p] = 0;
    __syncthreads();

    int d[EPT];
    #pragma unroll
    for (int i = 0; i < EPT; ++i) {
        int e = e0 + i * BT + t;
        if (e < N_EDGES) {
            d[i] = dst[e];
            atomicAdd(&lhist[d[i] >> 7], 1);       // LDS int, non-returning
        } else {
            d[i] = -1;
        }
    }
    __syncthreads();

    for (int p = t; p < NP; p += BT) {
        int c = lhist[p];
        gb[p] = c ? atomicAdd(&pcursor[p * CSTRIDE], c) : 0;  // block-granular
        lhist[p] = 0;
    }
    __syncthreads();

    #pragma unroll
    for (int i = 0; i < EPT; ++i) {
        if (d[i] >= 0) {
            int e = e0 + i * BT + t;
            int p = d[i] >> 7;
            int loc = atomicAdd(&lhist[p], 1);     // LDS int, returning (native)
            ebuf[p * SLOT + gb[p] + loc] = (src[e] << 7) | (d[i] & 127);
        }
    }
}

// ---- Pass 2: one block per partition. Build 128-node CSR in LDS (int
// atomics only), then round-8-proven gather: wave per 8 nodes, 8 row-slots x
// ushort8 chunks (1 KB/instruction), fp32 REGISTER accumulation, shfl-reduce
// epilogue. No float atomics anywhere.
__global__ __launch_bounds__(1024, 8)
void aggregate_kernel(const ushort8* __restrict__ xh8,
                      const int* __restrict__ pcursor,
                      const int* __restrict__ ebuf,
                      float* __restrict__ out) {
    __shared__ int lraw[SLOT];    // raw packed edges (8 KB)
    __shared__ int lcsr[SLOT];    // src ids, CSR-ordered (8 KB)
    __shared__ int lhist[PART];   // counts -> inclusive prefix
    __shared__ int lcur[PART];
    int p = blockIdx.x;
    int t = threadIdx.x;
    int wave = t >> 6, lane = t & 63;
    int g = lane >> 3, sub = lane & 7;

    if (t < PART) lhist[t] = 0;
    __syncthreads();

    int cnt = pcursor[p * CSTRIDE];
    const int* __restrict__ eb = ebuf + p * SLOT;
    for (int i = t; i < cnt; i += 1024) {
        int pk = eb[i];
        lraw[i] = pk;
        atomicAdd(&lhist[pk & 127], 1);
    }
    __syncthreads();

    // inclusive Hillis-Steele scan over 128 bins
    for (int off = 1; off < PART; off <<= 1) {
        int v = 0;
        if (t < PART) { v = lhist[t]; if (t >= off) v += lhist[t - off]; }
        __syncthreads();
        if (t < PART) lhist[t] = v;
        __syncthreads();
    }
    if (t < PART) lcur[t] = (t > 0) ? lhist[t - 1] : 0;
    __syncthreads();

    for (int i = t; i < cnt; i += 1024) {
        int pk = lraw[i];
        int pos = atomicAdd(&lcur[pk & 127], 1);   // LDS int, returning
        lcsr[pos] = pk >> 7;
    }
    __syncthreads();

    // each wave processes 8 consecutive local nodes
    for (int q = 0; q < 8; ++q) {
        int nl = wave * 8 + q;
        int gnode = p * PART + nl;
        if (gnode >= N_NODES) break;               // wave-uniform
        int s0 = (nl > 0) ? lhist[nl - 1] : 0;     // LDS broadcast
        int dn = lhist[nl] - s0;

        float acc[8] = {0.f, 0.f, 0.f, 0.f, 0.f, 0.f, 0.f, 0.f};
        int e = g;
        for (; e + 8 < dn; e += 16) {
            int a = lcsr[s0 + e];
            int b = lcsr[s0 + e + 8];
            ushort8 v0 = xh8[(size_t)a * 8 + sub];
            ushort8 v1 = xh8[(size_t)b * 8 + sub];
            #pragma unroll
            for (int k = 0; k < 8; ++k) acc[k] += bf2f(v0[k]) + bf2f(v1[k]);
        }
        if (e < dn) {
            int a = lcsr[s0 + e];
            ushort8 v0 = xh8[(size_t)a * 8 + sub];
            #pragma unroll
            for (int k = 0; k < 8; ++k) acc[k] += bf2f(v0[k]);
        }

        #pragma unroll
        for (int off = 8; off < 64; off <<= 1) {
            #pragma unroll
            for (int k = 0; k < 8; ++k) acc[k] += __shfl_xor(acc[k], off, 64);
        }

        float inv = 1.0f / fmaxf((float)dn, 1.0f);
        #pragma unroll
        for (int k = 0; k < 8; ++k) acc[k] *= inv;

        float ss = 0.f;
        #pragma unroll
        for (int k = 0; k < 8; ++k) ss += acc[k] * acc[k];
        #pragma unroll
        for (int off = 1; off < 8; off <<= 1) ss += __shfl_xor(ss, off, 64);

        float scale = 2.0f / fmaxf(sqrtf(ss), EPS);
        if (g == 0) {
            float4 o0, o1;
            o0.x = fmaxf(acc[0] * scale, 0.0f); o0.y = fmaxf(acc[1] * scale, 0.0f);
            o0.z = fmaxf(acc[2] * scale, 0.0f); o0.w = fmaxf(acc[3] * scale, 0.0f);
            o1.x = fmaxf(acc[4] * scale, 0.0f); o1.y = fmaxf(acc[5] * scale, 0.0f);
            o1.z = fmaxf(acc[6] * scale, 0.0f); o1.w = fmaxf(acc[7] * scale, 0.0f);
            ((float4*)out)[(size_t)gnode * 16 + 2 * sub]     = o0;
            ((float4*)out)[(size_t)gnode * 16 + 2 * sub + 1] = o1;
        }
    }
}

extern "C" void kernel_launch(void* const* d_in, const int* in_sizes, int n_in,
                              void* d_out, int out_size, void* d_ws, size_t ws_size,
                              hipStream_t stream) {
    const float* x  = (const float*)d_in[0];
    const int*   ei = (const int*)d_in[1];
    float* out = (float*)d_out;

    const int* src = ei;
    const int* dst = ei + N_EDGES;

    // ws: xh[12.8 MB bf16] | pcursor[782*16 ints, line-padded = 50 KB] |
    //     ebuf[782*2048 int = 6.4 MB]
    ushort8* xh  = (ushort8*)d_ws;
    int* pcursor = (int*)((char*)d_ws + (size_t)N_NODES * DIM * 2);
    int* ebuf    = pcursor + NP * CSTRIDE;

    hipMemsetAsync(pcursor, 0, NP * CSTRIDE * sizeof(int), stream);

    int cvb = (N_NODES * DIM / 8 + 255) / 256;
    convert_kernel<<<cvb, 256, 0, stream>>>((const float4*)x, xh);

    bucket_kernel<<<NCH, BT, 0, stream>>>(src, dst, pcursor, ebuf);

    aggregate_kernel<<<NP, 1024, 0, stream>>>(xh, pcursor, ebuf, out);
}

// Round 11
// 163.593 us; speedup vs baseline: 3.9253x; 1.0671x over previous
//
#include <hip/hip_runtime.h>

#define N_NODES 100000
#define DIM 64
#define N_EDGES 1250000
#define EPS 1e-12f

#define PART 128                          // nodes per partition
#define NP ((N_NODES + PART - 1) / PART)  // 782 partitions
#define SLOT 2048                         // edge slots/partition (mean 1600, +11 sigma)
#define CSTRIDE 16                        // pcursor padding: 1 cursor per 64B line
#define CH 8192                           // edges per bucket block
#define NCH ((N_EDGES + CH - 1) / CH)     // 153 bucket blocks
#define BT 1024                           // bucket block threads
#define EPT (CH / BT)                     // 8 edges per thread

typedef unsigned short ushort8 __attribute__((ext_vector_type(8)));

__device__ inline unsigned short f2bf(float f) {   // fp32 -> bf16 RNE
    unsigned int u = __float_as_uint(f);
    return (unsigned short)((u + 0x7FFFu + ((u >> 16) & 1u)) >> 16);
}
__device__ inline float bf2f(unsigned short h) {
    return __uint_as_float(((unsigned int)h) << 16);
}

// ---- Pass 0: x (fp32) -> xh (bf16); halves gather traffic ----
__global__ void convert_kernel(const float4* __restrict__ x4,
                               ushort8* __restrict__ xh8) {
    int i = blockIdx.x * blockDim.x + threadIdx.x;
    if (i < N_NODES * DIM / 8) {
        float4 a = x4[2 * i];
        float4 b = x4[2 * i + 1];
        ushort8 o;
        o[0] = f2bf(a.x); o[1] = f2bf(a.y); o[2] = f2bf(a.z); o[3] = f2bf(a.w);
        o[4] = f2bf(b.x); o[5] = f2bf(b.y); o[6] = f2bf(b.z); o[7] = f2bf(b.w);
        xh8[i] = o;
    }
}

// ---- Pass 1: bucket edges by dst partition, SORTED IN LDS first.
// Round-10's per-edge scattered global store (64 lines per wave-store,
// ~80 MB allocate) was ~50 us; here edges are counting-sorted into LDS,
// then each wave dumps whole per-partition runs (~10 consecutive ints) —
// contiguous global stores. Global returning atomics: 153x782 ~ 120K,
// block-granular, well under the measured ~25 G ops/s wall.
__global__ __launch_bounds__(BT)
void bucket_kernel(const int* __restrict__ src,
                   const int* __restrict__ dst,
                   int* __restrict__ pcursor,
                   int* __restrict__ ebuf) {
    __shared__ int hist[NP];      // per-bin count (stable after pass A)
    __shared__ int lstart[NP];    // exclusive prefix -> LDS run start
    __shared__ int cur[NP];       // placement cursor / scan scratch
    __shared__ int gb[NP];        // global base in partition slab
    __shared__ int sorted[CH];    // packed edges grouped by partition (32 KB)
    int t = threadIdx.x;
    int e0 = blockIdx.x * CH;

    for (int p = t; p < NP; p += BT) hist[p] = 0;
    __syncthreads();

    int d[EPT];
    #pragma unroll
    for (int i = 0; i < EPT; ++i) {
        int e = e0 + i * BT + t;
        d[i] = (e < N_EDGES) ? dst[e] : -1;
        if (d[i] >= 0) atomicAdd(&hist[d[i] >> 7], 1);   // LDS, non-returning
    }
    __syncthreads();

    // global slab base per bin (overlaps with the scan below)
    for (int p = t; p < NP; p += BT) {
        int c = hist[p];
        gb[p] = c ? atomicAdd(&pcursor[p * CSTRIDE], c) : 0;
    }
    // Hillis-Steele inclusive scan of hist (copy in cur), NP=782 < BT
    for (int p = t; p < NP; p += BT) cur[p] = hist[p];
    __syncthreads();
    for (int off = 1; off < NP; off <<= 1) {
        int v = 0;
        if (t < NP) { v = cur[t]; if (t >= off) v += cur[t - off]; }
        __syncthreads();
        if (t < NP) cur[t] = v;
        __syncthreads();
    }
    if (t < NP) lstart[t] = (t > 0) ? cur[t - 1] : 0;
    __syncthreads();
    if (t < NP) cur[t] = lstart[t];
    __syncthreads();

    // place into LDS (native int LDS atomics)
    #pragma unroll
    for (int i = 0; i < EPT; ++i) {
        if (d[i] >= 0) {
            int e = e0 + i * BT + t;
            int p = d[i] >> 7;
            int pos = atomicAdd(&cur[p], 1);
            sorted[pos] = (src[e] << 7) | (d[i] & 127);
        }
    }
    __syncthreads();

    // dump: wave per bin, lanes stride the run -> contiguous global stores
    int wave = t >> 6, lane = t & 63;
    for (int p = wave; p < NP; p += (BT / 64)) {
        int c = hist[p];
        int base = p * SLOT + gb[p];
        int ls = lstart[p];
        for (int off = lane; off < c; off += 64)
            ebuf[base + off] = sorted[ls + off];
    }
}

// ---- Pass 2: one block per partition. Build 128-node CSR in LDS, then
// gather with node-PAIR processing (4 outstanding 16 B loads/lane). The
// mean division cancels in L2-normalize (a/d / ||a/d|| == a/||a||), so no
// degree bookkeeping in the epilogue at all.
__global__ __launch_bounds__(1024, 8)
void aggregate_kernel(const ushort8* __restrict__ xh8,
                      const int* __restrict__ pcursor,
                      const int* __restrict__ ebuf,
                      float* __restrict__ out) {
    __shared__ int lraw[SLOT];    // raw packed edges (8 KB)
    __shared__ int lcsr[SLOT];    // src ids, CSR-ordered (8 KB)
    __shared__ int lhist[PART];   // counts -> inclusive prefix
    __shared__ int lcur[PART];
    int p = blockIdx.x;
    int t = threadIdx.x;
    int wave = t >> 6, lane = t & 63;
    int g = lane >> 3, sub = lane & 7;

    if (t < PART) lhist[t] = 0;
    __syncthreads();

    int cnt = pcursor[p * CSTRIDE];
    const int* __restrict__ eb = ebuf + p * SLOT;
    for (int i = t; i < cnt; i += 1024) {
        int pk = eb[i];
        lraw[i] = pk;
        atomicAdd(&lhist[pk & 127], 1);
    }
    __syncthreads();

    for (int off = 1; off < PART; off <<= 1) {
        int v = 0;
        if (t < PART) { v = lhist[t]; if (t >= off) v += lhist[t - off]; }
        __syncthreads();
        if (t < PART) lhist[t] = v;
        __syncthreads();
    }
    if (t < PART) lcur[t] = (t > 0) ? lhist[t - 1] : 0;
    __syncthreads();

    for (int i = t; i < cnt; i += 1024) {
        int pk = lraw[i];
        int pos = atomicAdd(&lcur[pk & 127], 1);
        lcsr[pos] = pk >> 7;
    }
    __syncthreads();

    // each wave: 8 consecutive local nodes, processed in PAIRS
    for (int q = 0; q < 8; q += 2) {
        int nl0 = wave * 8 + q;
        int gn0 = p * PART + nl0;
        if (gn0 >= N_NODES) break;               // wave-uniform
        int beg0 = nl0 ? lhist[nl0 - 1] : 0;
        int end0 = lhist[nl0];
        int beg1 = end0;
        int end1 = lhist[nl0 + 1];
        int dn0 = end0 - beg0;
        int dn1 = end1 - beg1;
        bool n1ok = (gn0 + 1) < N_NODES;
        if (!n1ok) dn1 = 0;

        float acc0[8] = {0.f,0.f,0.f,0.f,0.f,0.f,0.f,0.f};
        float acc1[8] = {0.f,0.f,0.f,0.f,0.f,0.f,0.f,0.f};

        int mn = min(dn0, dn1);
        int e = g;
        for (; e + 8 < mn; e += 16) {            // 4 loads in flight
            int a0 = lcsr[beg0 + e];
            int a1 = lcsr[beg0 + e + 8];
            int b0 = lcsr[beg1 + e];
            int b1 = lcsr[beg1 + e + 8];
            ushort8 va0 = xh8[(size_t)a0 * 8 + sub];
            ushort8 va1 = xh8[(size_t)a1 * 8 + sub];
            ushort8 vb0 = xh8[(size_t)b0 * 8 + sub];
            ushort8 vb1 = xh8[(size_t)b1 * 8 + sub];
            #pragma unroll
            for (int k = 0; k < 8; ++k) {
                acc0[k] += bf2f(va0[k]) + bf2f(va1[k]);
                acc1[k] += bf2f(vb0[k]) + bf2f(vb1[k]);
            }
        }
        for (; e < dn0 || e < dn1; e += 8) {     // predicated tails, 2 loads
            if (e < dn0) {
                int a = lcsr[beg0 + e];
                ushort8 v = xh8[(size_t)a * 8 + sub];
                #pragma unroll
                for (int k = 0; k < 8; ++k) acc0[k] += bf2f(v[k]);
            }
            if (e < dn1) {
                int b = lcsr[beg1 + e];
                ushort8 v = xh8[(size_t)b * 8 + sub];
                #pragma unroll
                for (int k = 0; k < 8; ++k) acc1[k] += bf2f(v[k]);
            }
        }

        #pragma unroll
        for (int off = 8; off < 64; off <<= 1) {
            #pragma unroll
            for (int k = 0; k < 8; ++k) {
                acc0[k] += __shfl_xor(acc0[k], off, 64);
                acc1[k] += __shfl_xor(acc1[k], off, 64);
            }
        }

        float ss0 = 0.f, ss1 = 0.f;
        #pragma unroll
        for (int k = 0; k < 8; ++k) { ss0 += acc0[k]*acc0[k]; ss1 += acc1[k]*acc1[k]; }
        #pragma unroll
        for (int off = 1; off < 8; off <<= 1) {
            ss0 += __shfl_xor(ss0, off, 64);
            ss1 += __shfl_xor(ss1, off, 64);
        }

        float sc0 = 2.0f / fmaxf(sqrtf(ss0), EPS);
        float sc1 = 2.0f / fmaxf(sqrtf(ss1), EPS);
        if (g == 0) {
            float4 o;
            o.x = fmaxf(acc0[0]*sc0, 0.f); o.y = fmaxf(acc0[1]*sc0, 0.f);
            o.z = fmaxf(acc0[2]*sc0, 0.f); o.w = fmaxf(acc0[3]*sc0, 0.f);
            ((float4*)out)[(size_t)gn0 * 16 + 2*sub] = o;
            o.x = fmaxf(acc0[4]*sc0, 0.f); o.y = fmaxf(acc0[5]*sc0, 0.f);
            o.z = fmaxf(acc0[6]*sc0, 0.f); o.w = fmaxf(acc0[7]*sc0, 0.f);
            ((float4*)out)[(size_t)gn0 * 16 + 2*sub + 1] = o;
            if (n1ok) {
                o.x = fmaxf(acc1[0]*sc1, 0.f); o.y = fmaxf(acc1[1]*sc1, 0.f);
                o.z = fmaxf(acc1[2]*sc1, 0.f); o.w = fmaxf(acc1[3]*sc1, 0.f);
                ((float4*)out)[(size_t)(gn0+1) * 16 + 2*sub] = o;
                o.x = fmaxf(acc1[4]*sc1, 0.f); o.y = fmaxf(acc1[5]*sc1, 0.f);
                o.z = fmaxf(acc1[6]*sc1, 0.f); o.w = fmaxf(acc1[7]*sc1, 0.f);
                ((float4*)out)[(size_t)(gn0+1) * 16 + 2*sub + 1] = o;
            }
        }
    }
}

extern "C" void kernel_launch(void* const* d_in, const int* in_sizes, int n_in,
                              void* d_out, int out_size, void* d_ws, size_t ws_size,
                              hipStream_t stream) {
    const float* x  = (const float*)d_in[0];
    const int*   ei = (const int*)d_in[1];
    float* out = (float*)d_out;

    const int* src = ei;
    const int* dst = ei + N_EDGES;

    // ws: xh[12.8 MB bf16] | pcursor[782*16 ints, line-padded] | ebuf[6.4 MB]
    ushort8* xh  = (ushort8*)d_ws;
    int* pcursor = (int*)((char*)d_ws + (size_t)N_NODES * DIM * 2);
    int* ebuf    = pcursor + NP * CSTRIDE;

    hipMemsetAsync(pcursor, 0, NP * CSTRIDE * sizeof(int), stream);

    int cvb = (N_NODES * DIM / 8 + 255) / 256;
    convert_kernel<<<cvb, 256, 0, stream>>>((const float4*)x, xh);

    bucket_kernel<<<NCH, BT, 0, stream>>>(src, dst, pcursor, ebuf);

    aggregate_kernel<<<NP, 1024, 0, stream>>>(xh, pcursor, ebuf, out);
}

// Round 12
// 150.275 us; speedup vs baseline: 4.2732x; 1.0886x over previous
//
#include <hip/hip_runtime.h>

#define N_NODES 100000
#define DIM 64
#define N_EDGES 1250000
#define EPS 1e-12f

#define PART 128                          // nodes per partition
#define NP ((N_NODES + PART - 1) / PART)  // 782 partitions
#define SLOT 2048                         // edge slots/partition (mean 1600, +11 sigma)
#define CSTRIDE 16                        // pcursor padding: 1 cursor per 64B line
#define CH 4096                           // edges per bucket block
#define NCH ((N_EDGES + CH - 1) / CH)     // 306 bucket blocks (full CU coverage)
#define BT 1024                           // bucket block threads
#define EPT (CH / BT)                     // 4 edges per thread

typedef unsigned short ushort8 __attribute__((ext_vector_type(8)));

__device__ inline unsigned short f2bf(float f) {   // fp32 -> bf16 RNE
    unsigned int u = __float_as_uint(f);
    return (unsigned short)((u + 0x7FFFu + ((u >> 16) & 1u)) >> 16);
}
__device__ inline float bf2f(unsigned short h) {
    return __uint_as_float(((unsigned int)h) << 16);
}

// ---- Pass 0: x (fp32) -> xh (bf16); halves gather footprint ----
__global__ void convert_kernel(const float4* __restrict__ x4,
                               ushort8* __restrict__ xh8) {
    int i = blockIdx.x * blockDim.x + threadIdx.x;
    if (i < N_NODES * DIM / 8) {
        float4 a = x4[2 * i];
        float4 b = x4[2 * i + 1];
        ushort8 o;
        o[0] = f2bf(a.x); o[1] = f2bf(a.y); o[2] = f2bf(a.z); o[3] = f2bf(a.w);
        o[4] = f2bf(b.x); o[5] = f2bf(b.y); o[6] = f2bf(b.z); o[7] = f2bf(b.w);
        xh8[i] = o;
    }
}

// ---- Pass 1: bucket edges by dst partition, counting-sorted in LDS, then
// dumped as contiguous per-partition runs. 306 blocks cover all 256 CUs
// (round-11's 153 left 40% idle). Global returning atomics: 306x782 = 239K
// block-granular — 5x under the measured ~25 G ops/s per-edge wall.
__global__ __launch_bounds__(BT)
void bucket_kernel(const int* __restrict__ src,
                   const int* __restrict__ dst,
                   int* __restrict__ pcursor,
                   int* __restrict__ ebuf) {
    __shared__ int hist[NP];      // per-bin count (stable after pass A)
    __shared__ int lstart[NP];    // exclusive prefix -> LDS run start
    __shared__ int cur[NP];       // placement cursor / scan scratch
    __shared__ int gb[NP];        // global base in partition slab
    __shared__ int sorted[CH];    // packed edges grouped by partition (16 KB)
    int t = threadIdx.x;
    int e0 = blockIdx.x * CH;

    for (int p = t; p < NP; p += BT) hist[p] = 0;
    __syncthreads();

    int d[EPT];
    #pragma unroll
    for (int i = 0; i < EPT; ++i) {
        int e = e0 + i * BT + t;
        d[i] = (e < N_EDGES) ? dst[e] : -1;
        if (d[i] >= 0) atomicAdd(&hist[d[i] >> 7], 1);   // LDS, non-returning
    }
    __syncthreads();

    // global slab base per bin
    for (int p = t; p < NP; p += BT) {
        int c = hist[p];
        gb[p] = c ? atomicAdd(&pcursor[p * CSTRIDE], c) : 0;
    }
    // Hillis-Steele inclusive scan of hist (in cur); NP=782 < BT=1024
    for (int p = t; p < NP; p += BT) cur[p] = hist[p];
    __syncthreads();
    for (int off = 1; off < NP; off <<= 1) {
        int v = 0;
        if (t < NP) { v = cur[t]; if (t >= off) v += cur[t - off]; }
        __syncthreads();
        if (t < NP) cur[t] = v;
        __syncthreads();
    }
    if (t < NP) lstart[t] = (t > 0) ? cur[t - 1] : 0;
    __syncthreads();
    if (t < NP) cur[t] = lstart[t];
    __syncthreads();

    // place into LDS (native int LDS atomics)
    #pragma unroll
    for (int i = 0; i < EPT; ++i) {
        if (d[i] >= 0) {
            int e = e0 + i * BT + t;
            int p = d[i] >> 7;
            int pos = atomicAdd(&cur[p], 1);
            sorted[pos] = (src[e] << 7) | (d[i] & 127);
        }
    }
    __syncthreads();

    // dump: wave per bin, lanes stride the run -> contiguous global stores
    int wave = t >> 6, lane = t & 63;
    for (int p = wave; p < NP; p += (BT / 64)) {
        int c = hist[p];
        int base = p * SLOT + gb[p];
        int ls = lstart[p];
        for (int off = lane; off < c; off += 64)
            ebuf[base + off] = sorted[ls + off];
    }
}

// ---- Pass 2: one block per partition. Build 128-node CSR in LDS, then
// gather with node-per-lane-group layout: lane = (n = lane>>3, sub = lane&7);
// each 8-lane group owns one node and issues 4 independent predicated row
// loads per trip. Each lane ends holding its node's partial over its 8 dims
// — NO cross-group sum reduce at all; only a 3-shfl sumsq reduce. The mean
// division cancels in L2-normalize, so no degree use in the epilogue.
__global__ __launch_bounds__(1024, 8)
void aggregate_kernel(const ushort8* __restrict__ xh8,
                      const int* __restrict__ pcursor,
                      const int* __restrict__ ebuf,
                      float* __restrict__ out) {
    __shared__ int lraw[SLOT];    // raw packed edges (8 KB)
    __shared__ int lcsr[SLOT];    // src ids, CSR-ordered (8 KB)
    __shared__ int lhist[PART];   // counts -> inclusive prefix
    __shared__ int lcur[PART];
    int p = blockIdx.x;
    int t = threadIdx.x;
    int wave = t >> 6, lane = t & 63;
    int n = lane >> 3;            // node slot within the wave's octet
    int sub = lane & 7;           // ushort8 chunk (dims sub*8 .. sub*8+7)

    if (t < PART) lhist[t] = 0;
    __syncthreads();

    int cnt = pcursor[p * CSTRIDE];
    const int* __restrict__ eb = ebuf + p * SLOT;
    for (int i = t; i < cnt; i += 1024) {
        int pk = eb[i];
        lraw[i] = pk;
        atomicAdd(&lhist[pk & 127], 1);
    }
    __syncthreads();

    for (int off = 1; off < PART; off <<= 1) {
        int v = 0;
        if (t < PART) { v = lhist[t]; if (t >= off) v += lhist[t - off]; }
        __syncthreads();
        if (t < PART) lhist[t] = v;
        __syncthreads();
    }
    if (t < PART) lcur[t] = (t > 0) ? lhist[t - 1] : 0;
    __syncthreads();

    for (int i = t; i < cnt; i += 1024) {
        int pk = lraw[i];
        int pos = atomicAdd(&lcur[pk & 127], 1);
        lcsr[pos] = pk >> 7;
    }
    __syncthreads();

    int nl = wave * 8 + n;                   // local node 0..127
    int gnode = p * PART + nl;
    int beg = nl ? lhist[nl - 1] : 0;        // LDS broadcast within group
    int dn  = lhist[nl] - beg;

    float acc[8] = {0.f,0.f,0.f,0.f,0.f,0.f,0.f,0.f};
    for (int e = 0; e < dn; e += 4) {
        #pragma unroll
        for (int i = 0; i < 4; ++i) {
            if (e + i < dn) {
                int s = lcsr[beg + e + i];
                ushort8 v = xh8[(size_t)s * 8 + sub];
                #pragma unroll
                for (int k = 0; k < 8; ++k) acc[k] += bf2f(v[k]);
            }
        }
    }

    float ss = 0.f;
    #pragma unroll
    for (int k = 0; k < 8; ++k) ss += acc[k] * acc[k];
    ss += __shfl_xor(ss, 1, 64);             // reduce across the 8-lane group
    ss += __shfl_xor(ss, 2, 64);
    ss += __shfl_xor(ss, 4, 64);

    float scale = 2.0f / fmaxf(sqrtf(ss), EPS);
    if (gnode < N_NODES) {
        float4 o0, o1;
        o0.x = fmaxf(acc[0] * scale, 0.f); o0.y = fmaxf(acc[1] * scale, 0.f);
        o0.z = fmaxf(acc[2] * scale, 0.f); o0.w = fmaxf(acc[3] * scale, 0.f);
        o1.x = fmaxf(acc[4] * scale, 0.f); o1.y = fmaxf(acc[5] * scale, 0.f);
        o1.z = fmaxf(acc[6] * scale, 0.f); o1.w = fmaxf(acc[7] * scale, 0.f);
        ((float4*)out)[(size_t)gnode * 16 + 2 * sub]     = o0;
        ((float4*)out)[(size_t)gnode * 16 + 2 * sub + 1] = o1;
    }
}

extern "C" void kernel_launch(void* const* d_in, const int* in_sizes, int n_in,
                              void* d_out, int out_size, void* d_ws, size_t ws_size,
                              hipStream_t stream) {
    const float* x  = (const float*)d_in[0];
    const int*   ei = (const int*)d_in[1];
    float* out = (float*)d_out;

    const int* src = ei;
    const int* dst = ei + N_EDGES;

    // ws: xh[12.8 MB bf16] | pcursor[782*16 ints, line-padded] | ebuf[6.4 MB]
    ushort8* xh  = (ushort8*)d_ws;
    int* pcursor = (int*)((char*)d_ws + (size_t)N_NODES * DIM * 2);
    int* ebuf    = pcursor + NP * CSTRIDE;

    hipMemsetAsync(pcursor, 0, NP * CSTRIDE * sizeof(int), stream);

    int cvb = (N_NODES * DIM / 8 + 255) / 256;
    convert_kernel<<<cvb, 256, 0, stream>>>((const float4*)x, xh);

    bucket_kernel<<<NCH, BT, 0, stream>>>(src, dst, pcursor, ebuf);

    aggregate_kernel<<<NP, 1024, 0, stream>>>(xh, pcursor, ebuf, out);
}

// Round 13
// 132.844 us; speedup vs baseline: 4.8339x; 1.1312x over previous
//
#include <hip/hip_runtime.h>

#define N_NODES 100000
#define DIM 64
#define N_EDGES 1250000
#define EPS 1e-12f

#define PART 128                          // nodes per partition
#define NP ((N_NODES + PART - 1) / PART)  // 782 partitions
#define SLOT 2048                         // edge slots/partition (mean 1600, +11 sigma)
#define CSTRIDE 16                        // pcursor padding: 1 cursor per 64B line
#define CH 4096                           // edges per bucket block
#define NCH ((N_EDGES + CH - 1) / CH)     // 306 bucket blocks
#define BT 512                            // threads (8 waves -> 4 blocks/CU)
#define EPT (CH / BT)                     // 8 edges per thread
#define NCV ((N_NODES * DIM / 8 + BT - 1) / BT)   // 1563 convert blocks

typedef unsigned short ushort8 __attribute__((ext_vector_type(8)));

__device__ inline unsigned short f2bf(float f) {   // fp32 -> bf16 RNE
    unsigned int u = __float_as_uint(f);
    return (unsigned short)((u + 0x7FFFu + ((u >> 16) & 1u)) >> 16);
}
__device__ inline float bf2f(unsigned short h) {
    return __uint_as_float(((unsigned int)h) << 16);
}

// ---- Pass 1 (fused): blocks [0,NCH) bucket edges by dst partition (LDS
// counting sort, fully-parallel coalesced dump); blocks [NCH,..) stream-
// convert x fp32 -> bf16. The two workloads are independent and
// complementary (LDS/atomic vs pure HBM), so they overlap on the device.
__global__ __launch_bounds__(BT)
void convert_bucket_kernel(const float4* __restrict__ x4,
                           ushort8* __restrict__ xh8,
                           const int* __restrict__ src,
                           const int* __restrict__ dst,
                           int* __restrict__ pcursor,
                           int* __restrict__ ebuf) {
    __shared__ int hist[NP];               // per-bin counts
    __shared__ int lstart[NP];             // exclusive prefix (LDS run start)
    __shared__ int cur[NP];                // placement cursors
    __shared__ int gb[NP];                 // global slab base per bin
    __shared__ int sorted[CH];             // packed edges grouped by bin (16 KB)
    __shared__ unsigned short pb[CH];      // bin id per sorted slot (8 KB)
    __shared__ int wsum[BT / 64];

    int t = threadIdx.x;

    if (blockIdx.x >= NCH) {               // ---- convert branch ----
        int i = (blockIdx.x - NCH) * BT + t;
        if (i < N_NODES * DIM / 8) {
            float4 a = x4[2 * i];
            float4 b = x4[2 * i + 1];
            ushort8 o;
            o[0] = f2bf(a.x); o[1] = f2bf(a.y); o[2] = f2bf(a.z); o[3] = f2bf(a.w);
            o[4] = f2bf(b.x); o[5] = f2bf(b.y); o[6] = f2bf(b.z); o[7] = f2bf(b.w);
            xh8[i] = o;
        }
        return;
    }

    // ---- bucket branch ----
    int e0 = blockIdx.x * CH;
    for (int p = t; p < NP; p += BT) hist[p] = 0;
    __syncthreads();

    int d[EPT];
    #pragma unroll
    for (int i = 0; i < EPT; ++i) {
        int e = e0 + i * BT + t;
        d[i] = (e < N_EDGES) ? dst[e] : -1;
        if (d[i] >= 0) atomicAdd(&hist[d[i] >> 7], 1);   // LDS, non-returning
    }
    __syncthreads();

    // global slab base per bin (block-granular returning atomics: 306x782)
    for (int p = t; p < NP; p += BT) {
        int c = hist[p];
        gb[p] = c ? atomicAdd(&pcursor[p * CSTRIDE], c) : 0;
    }

    // shfl-based exclusive scan over 782 bins, 2 bins/thread, 2 barriers
    int lane = t & 63, w = t >> 6;
    int b0 = 2 * t, b1 = 2 * t + 1;
    int c0 = (b0 < NP) ? hist[b0] : 0;
    int c1 = (b1 < NP) ? hist[b1] : 0;
    int ms = c0 + c1;
    int v = ms;
    #pragma unroll
    for (int off = 1; off < 64; off <<= 1) {
        int u = __shfl_up(v, off, 64);
        if (lane >= off) v += u;
    }
    if (lane == 63) wsum[w] = v;
    __syncthreads();
    if (t == 0) {
        int run = 0;
        #pragma unroll
        for (int i = 0; i < BT / 64; ++i) { int c = wsum[i]; wsum[i] = run; run += c; }
    }
    __syncthreads();
    int excl = wsum[w] + v - ms;
    if (b0 < NP) { lstart[b0] = excl;      cur[b0] = excl; }
    if (b1 < NP) { lstart[b1] = excl + c0; cur[b1] = excl + c0; }
    __syncthreads();

    // place into LDS (native int LDS atomics), record bin per slot
    #pragma unroll
    for (int i = 0; i < EPT; ++i) {
        if (d[i] >= 0) {
            int e = e0 + i * BT + t;
            int p = d[i] >> 7;
            int pos = atomicAdd(&cur[p], 1);
            sorted[pos] = (src[e] << 7) | (d[i] & 127);
            pb[pos] = (unsigned short)p;
        }
    }
    __syncthreads();

    // fully-parallel dump: every thread stores one element; consecutive
    // slots within a bin -> consecutive global addresses (runs ~5)
    int vcnt = min(CH, N_EDGES - e0);
    for (int i = t; i < vcnt; i += BT) {
        int pk = sorted[i];
        int p = pb[i];
        ebuf[p * SLOT + gb[p] + (i - lstart[p])] = pk;
    }
}

// ---- Pass 2: one 512-thread block per partition (4 blocks/CU -> 0.76
// resident rounds over 782 blocks). Build 128-node CSR in LDS (shfl scan,
// 2 barriers), then node-per-lane-group gather: 8-lane group owns one node,
// 4 independent predicated 128 B row loads in flight; no cross-group sum
// reduce (mean division cancels in L2-normalize).
__global__ __launch_bounds__(BT, 8)
void aggregate_kernel(const ushort8* __restrict__ xh8,
                      const int* __restrict__ pcursor,
                      const int* __restrict__ ebuf,
                      float* __restrict__ out) {
    __shared__ int lraw[SLOT];    // raw packed edges (8 KB)
    __shared__ int lcsr[SLOT];    // src ids, CSR-ordered (8 KB)
    __shared__ int lhist[PART];   // counts -> inclusive prefix
    __shared__ int lcur[PART];    // exclusive prefix -> placement cursor
    __shared__ int bridge;
    int p = blockIdx.x;
    int t = threadIdx.x;
    int lane = t & 63, w = t >> 6;
    int n = lane >> 3, sub = lane & 7;

    if (t < PART) lhist[t] = 0;
    __syncthreads();

    int cnt = pcursor[p * CSTRIDE];
    const int* __restrict__ eb = ebuf + p * SLOT;
    for (int i = t; i < cnt; i += BT) {
        int pk = eb[i];
        lraw[i] = pk;
        atomicAdd(&lhist[pk & 127], 1);
    }
    __syncthreads();

    // shfl scan over 128 bins (threads 0..127 = waves 0,1), 2 barriers
    int myc = 0, vincl = 0;
    if (t < PART) {
        myc = lhist[t];
        vincl = myc;
        #pragma unroll
        for (int off = 1; off < 64; off <<= 1) {
            int u = __shfl_up(vincl, off, 64);
            if (lane >= off) vincl += u;
        }
        if (t == 63) bridge = vincl;
    }
    __syncthreads();
    if (t < PART) {
        int add = (t >= 64) ? bridge : 0;
        lhist[t] = vincl + add;          // inclusive prefix
        lcur[t]  = vincl + add - myc;    // exclusive prefix
    }
    __syncthreads();

    for (int i = t; i < cnt; i += BT) {
        int pk = lraw[i];
        int pos = atomicAdd(&lcur[pk & 127], 1);
        lcsr[pos] = pk >> 7;
    }
    __syncthreads();

    // 8 waves x 8 groups = 64 nodes per q-pass; q=0,1 covers 128
    #pragma unroll
    for (int q = 0; q < 2; ++q) {
        int nl = q * 64 + w * 8 + n;
        int gnode = p * PART + nl;
        int beg = nl ? lhist[nl - 1] : 0;
        int dn  = lhist[nl] - beg;

        float acc[8] = {0.f,0.f,0.f,0.f,0.f,0.f,0.f,0.f};
        for (int e = 0; e < dn; e += 4) {
            #pragma unroll
            for (int i = 0; i < 4; ++i) {
                if (e + i < dn) {
                    int s = lcsr[beg + e + i];
                    ushort8 vv = xh8[(size_t)s * 8 + sub];
                    #pragma unroll
                    for (int k = 0; k < 8; ++k) acc[k] += bf2f(vv[k]);
                }
            }
        }

        float ss = 0.f;
        #pragma unroll
        for (int k = 0; k < 8; ++k) ss += acc[k] * acc[k];
        ss += __shfl_xor(ss, 1, 64);
        ss += __shfl_xor(ss, 2, 64);
        ss += __shfl_xor(ss, 4, 64);

        float scale = 2.0f / fmaxf(sqrtf(ss), EPS);
        if (gnode < N_NODES) {
            float4 o0, o1;
            o0.x = fmaxf(acc[0] * scale, 0.f); o0.y = fmaxf(acc[1] * scale, 0.f);
            o0.z = fmaxf(acc[2] * scale, 0.f); o0.w = fmaxf(acc[3] * scale, 0.f);
            o1.x = fmaxf(acc[4] * scale, 0.f); o1.y = fmaxf(acc[5] * scale, 0.f);
            o1.z = fmaxf(acc[6] * scale, 0.f); o1.w = fmaxf(acc[7] * scale, 0.f);
            ((float4*)out)[(size_t)gnode * 16 + 2 * sub]     = o0;
            ((float4*)out)[(size_t)gnode * 16 + 2 * sub + 1] = o1;
        }
    }
}

extern "C" void kernel_launch(void* const* d_in, const int* in_sizes, int n_in,
                              void* d_out, int out_size, void* d_ws, size_t ws_size,
                              hipStream_t stream) {
    const float* x  = (const float*)d_in[0];
    const int*   ei = (const int*)d_in[1];
    float* out = (float*)d_out;

    const int* src = ei;
    const int* dst = ei + N_EDGES;

    // ws: xh[12.8 MB bf16] | pcursor[782*16 ints, line-padded] | ebuf[6.4 MB]
    ushort8* xh  = (ushort8*)d_ws;
    int* pcursor = (int*)((char*)d_ws + (size_t)N_NODES * DIM * 2);
    int* ebuf    = pcursor + NP * CSTRIDE;

    hipMemsetAsync(pcursor, 0, NP * CSTRIDE * sizeof(int), stream);

    convert_bucket_kernel<<<NCH + NCV, BT, 0, stream>>>(
        (const float4*)x, xh, src, dst, pcursor, ebuf);

    aggregate_kernel<<<NP, BT, 0, stream>>>(xh, pcursor, ebuf, out);
}

// Round 15
// 131.632 us; speedup vs baseline: 4.8784x; 1.0092x over previous
//
#include <hip/hip_runtime.h>

#define N_NODES 100000
#define DIM 64
#define N_EDGES 1250000
#define EPS 1e-12f

#define PART 128                          // nodes per partition
#define NP ((N_NODES + PART - 1) / PART)  // 782 partitions
#define SLOT 2048                         // edge slots/partition (mean 1600, +11 sigma)
#define CSTRIDE 16                        // pcursor padding: 1 cursor per 64B line
#define CH 4096                           // edges per bucket block
#define NCH ((N_EDGES + CH - 1) / CH)     // 306 bucket blocks
#define BT 512                            // threads (8 waves -> 4 blocks/CU)
#define EPT (CH / BT)                     // 8 edges per thread
#define NCV ((N_NODES * DIM / 8 + BT - 1) / BT)   // 1563 convert blocks

typedef unsigned short ushort8 __attribute__((ext_vector_type(8)));

__device__ inline unsigned short f2bf(float f) {   // fp32 -> bf16 RNE
    unsigned int u = __float_as_uint(f);
    return (unsigned short)((u + 0x7FFFu + ((u >> 16) & 1u)) >> 16);
}
__device__ inline float bf2f(unsigned short h) {
    return __uint_as_float(((unsigned int)h) << 16);
}

// ---- Pass 1 (fused): blocks [0,NCH) bucket edges by dst partition (LDS
// counting sort, fully-parallel coalesced dump); blocks [NCH,..) stream-
// convert x fp32 -> bf16. Independent workloads overlap on the device.
// (Round-14 note: cooperative grid.sync fusion FAILS under graph capture —
// this 3-dispatch structure is the working floor.)
__global__ __launch_bounds__(BT)
void convert_bucket_kernel(const float4* __restrict__ x4,
                           ushort8* __restrict__ xh8,
                           const int* __restrict__ src,
                           const int* __restrict__ dst,
                           int* __restrict__ pcursor,
                           int* __restrict__ ebuf) {
    __shared__ int hist[NP];               // per-bin counts
    __shared__ int lstart[NP];             // exclusive prefix (LDS run start)
    __shared__ int cur[NP];                // placement cursors
    __shared__ int gb[NP];                 // global slab base per bin
    __shared__ int sorted[CH];             // packed edges grouped by bin (16 KB)
    __shared__ unsigned short pb[CH];      // bin id per sorted slot (8 KB)
    __shared__ int wsum[BT / 64];

    int t = threadIdx.x;

    if (blockIdx.x >= NCH) {               // ---- convert branch ----
        int i = (blockIdx.x - NCH) * BT + t;
        if (i < N_NODES * DIM / 8) {
            float4 a = x4[2 * i];
            float4 b = x4[2 * i + 1];
            ushort8 o;
            o[0] = f2bf(a.x); o[1] = f2bf(a.y); o[2] = f2bf(a.z); o[3] = f2bf(a.w);
            o[4] = f2bf(b.x); o[5] = f2bf(b.y); o[6] = f2bf(b.z); o[7] = f2bf(b.w);
            xh8[i] = o;
        }
        return;
    }

    // ---- bucket branch ----
    int e0 = blockIdx.x * CH;
    for (int p = t; p < NP; p += BT) hist[p] = 0;
    __syncthreads();

    int d[EPT];
    #pragma unroll
    for (int i = 0; i < EPT; ++i) {
        int e = e0 + i * BT + t;
        d[i] = (e < N_EDGES) ? dst[e] : -1;
        if (d[i] >= 0) atomicAdd(&hist[d[i] >> 7], 1);   // LDS, non-returning
    }
    __syncthreads();

    // global slab base per bin (block-granular returning atomics: 306x782)
    for (int p = t; p < NP; p += BT) {
        int c = hist[p];
        gb[p] = c ? atomicAdd(&pcursor[p * CSTRIDE], c) : 0;
    }

    // shfl-based exclusive scan over 782 bins, 2 bins/thread, 2 barriers
    int lane = t & 63, w = t >> 6;
    int b0 = 2 * t, b1 = 2 * t + 1;
    int c0 = (b0 < NP) ? hist[b0] : 0;
    int c1 = (b1 < NP) ? hist[b1] : 0;
    int ms = c0 + c1;
    int v = ms;
    #pragma unroll
    for (int off = 1; off < 64; off <<= 1) {
        int u = __shfl_up(v, off, 64);
        if (lane >= off) v += u;
    }
    if (lane == 63) wsum[w] = v;
    __syncthreads();
    if (t == 0) {
        int run = 0;
        #pragma unroll
        for (int i = 0; i < BT / 64; ++i) { int c = wsum[i]; wsum[i] = run; run += c; }
    }
    __syncthreads();
    int excl = wsum[w] + v - ms;
    if (b0 < NP) { lstart[b0] = excl;      cur[b0] = excl; }
    if (b1 < NP) { lstart[b1] = excl + c0; cur[b1] = excl + c0; }
    __syncthreads();

    // place into LDS (native int LDS atomics), record bin per slot
    #pragma unroll
    for (int i = 0; i < EPT; ++i) {
        if (d[i] >= 0) {
            int e = e0 + i * BT + t;
            int p = d[i] >> 7;
            int pos = atomicAdd(&cur[p], 1);
            sorted[pos] = (src[e] << 7) | (d[i] & 127);
            pb[pos] = (unsigned short)p;
        }
    }
    __syncthreads();

    // fully-parallel dump: every thread stores one element; consecutive
    // slots within a bin -> consecutive global addresses (runs ~5)
    int vcnt = min(CH, N_EDGES - e0);
    for (int i = t; i < vcnt; i += BT) {
        int pk = sorted[i];
        int p = pb[i];
        ebuf[p * SLOT + gb[p] + (i - lstart[p])] = pk;
    }
}

// ---- Pass 2: one 512-thread block per partition. Build 128-node CSR in
// LDS (shfl scan, 2 barriers), then node-per-lane-group gather with trips
// of EIGHT predicated row loads (mean deg 12.5 -> ~2 dependent trips vs 4
// at width 4). No cross-group sum reduce (mean cancels in L2-normalize).
__global__ __launch_bounds__(BT, 8)
void aggregate_kernel(const ushort8* __restrict__ xh8,
                      const int* __restrict__ pcursor,
                      const int* __restrict__ ebuf,
                      float* __restrict__ out) {
    __shared__ int lraw[SLOT];    // raw packed edges (8 KB)
    __shared__ int lcsr[SLOT];    // src ids, CSR-ordered (8 KB)
    __shared__ int lhist[PART];   // counts -> inclusive prefix
    __shared__ int lcur[PART];    // exclusive prefix -> placement cursor
    __shared__ int bridge;
    int p = blockIdx.x;
    int t = threadIdx.x;
    int lane = t & 63, w = t >> 6;
    int n = lane >> 3, sub = lane & 7;

    if (t < PART) lhist[t] = 0;
    __syncthreads();

    int cnt = pcursor[p * CSTRIDE];
    const int* __restrict__ eb = ebuf + p * SLOT;
    for (int i = t; i < cnt; i += BT) {
        int pk = eb[i];
        lraw[i] = pk;
        atomicAdd(&lhist[pk & 127], 1);
    }
    __syncthreads();

    // shfl scan over 128 bins (threads 0..127 = waves 0,1), 2 barriers
    int myc = 0, vincl = 0;
    if (t < PART) {
        myc = lhist[t];
        vincl = myc;
        #pragma unroll
        for (int off = 1; off < 64; off <<= 1) {
            int u = __shfl_up(vincl, off, 64);
            if (lane >= off) vincl += u;
        }
        if (t == 63) bridge = vincl;
    }
    __syncthreads();
    if (t < PART) {
        int add = (t >= 64) ? bridge : 0;
        lhist[t] = vincl + add;          // inclusive prefix
        lcur[t]  = vincl + add - myc;    // exclusive prefix
    }
    __syncthreads();

    for (int i = t; i < cnt; i += BT) {
        int pk = lraw[i];
        int pos = atomicAdd(&lcur[pk & 127], 1);
        lcsr[pos] = pk >> 7;
    }
    __syncthreads();

    // 8 waves x 8 groups = 64 nodes per q-pass; q=0,1 covers 128
    #pragma unroll
    for (int q = 0; q < 2; ++q) {
        int nl = q * 64 + w * 8 + n;
        int gnode = p * PART + nl;
        int beg = nl ? lhist[nl - 1] : 0;
        int dn  = lhist[nl] - beg;

        float acc[8] = {0.f,0.f,0.f,0.f,0.f,0.f,0.f,0.f};
        for (int e = 0; e < dn; e += 8) {
            #pragma unroll
            for (int i = 0; i < 8; ++i) {
                if (e + i < dn) {
                    int s = lcsr[beg + e + i];
                    ushort8 vv = xh8[(size_t)s * 8 + sub];
                    #pragma unroll
                    for (int k = 0; k < 8; ++k) acc[k] += bf2f(vv[k]);
                }
            }
        }

        float ss = 0.f;
        #pragma unroll
        for (int k = 0; k < 8; ++k) ss += acc[k] * acc[k];
        ss += __shfl_xor(ss, 1, 64);
        ss += __shfl_xor(ss, 2, 64);
        ss += __shfl_xor(ss, 4, 64);

        float scale = 2.0f / fmaxf(sqrtf(ss), EPS);
        if (gnode < N_NODES) {
            float4 o0, o1;
            o0.x = fmaxf(acc[0] * scale, 0.f); o0.y = fmaxf(acc[1] * scale, 0.f);
            o0.z = fmaxf(acc[2] * scale, 0.f); o0.w = fmaxf(acc[3] * scale, 0.f);
            o1.x = fmaxf(acc[4] * scale, 0.f); o1.y = fmaxf(acc[5] * scale, 0.f);
            o1.z = fmaxf(acc[6] * scale, 0.f); o1.w = fmaxf(acc[7] * scale, 0.f);
            ((float4*)out)[(size_t)gnode * 16 + 2 * sub]     = o0;
            ((float4*)out)[(size_t)gnode * 16 + 2 * sub + 1] = o1;
        }
    }
}

extern "C" void kernel_launch(void* const* d_in, const int* in_sizes, int n_in,
                              void* d_out, int out_size, void* d_ws, size_t ws_size,
                              hipStream_t stream) {
    const float* x  = (const float*)d_in[0];
    const int*   ei = (const int*)d_in[1];
    float* out = (float*)d_out;

    const int* src = ei;
    const int* dst = ei + N_EDGES;

    // ws: xh[12.8 MB bf16] | pcursor[782*16 ints, line-padded] | ebuf[6.4 MB]
    ushort8* xh  = (ushort8*)d_ws;
    int* pcursor = (int*)((char*)d_ws + (size_t)N_NODES * DIM * 2);
    int* ebuf    = pcursor + NP * CSTRIDE;

    hipMemsetAsync(pcursor, 0, NP * CSTRIDE * sizeof(int), stream);

    convert_bucket_kernel<<<NCH + NCV, BT, 0, stream>>>(
        (const float4*)x, xh, src, dst, pcursor, ebuf);

    aggregate_kernel<<<NP, BT, 0, stream>>>(xh, pcursor, ebuf, out);
}